// Round 18
// baseline (450.836 us; speedup 1.0000x reference)
//
#include <hip/hip_runtime.h>

#define EPS 1e-7f
#define NCH 29
#define SPB 128          // samples per block: 64 lanes x 2 packed (group0, group1)
#define ROWA 17          // padded float4 stride per sample in chunk staging buffer

// Diagnostic round: MODE 0 = full kernel, 1 = compute-only (no global stores,
// flush replaced by LDS reads kept alive), 2 = stores-only (MLP skipped,
// trivial obuf fill; full barrier+flush machinery). REP repeats the whole
// chunk loop to push ablated dispatches above the top-5 duration cutoff.

typedef float f32x2 __attribute__((ext_vector_type(2)));
typedef float nf4   __attribute__((ext_vector_type(4)));

__device__ __forceinline__ f32x2 splat2(float v) { f32x2 r; r.x = v; r.y = v; return r; }
__device__ __forceinline__ f32x2 fma2(f32x2 a, f32x2 b, f32x2 c) {
    return __builtin_elementwise_fma(a, b, c);
}
__device__ __forceinline__ f32x2 max2(f32x2 a, f32x2 b) {
    return __builtin_elementwise_max(a, b);
}
__device__ __forceinline__ f32x2 expc2(f32x2 a) {
    f32x2 r; r.x = __expf(a.x); r.y = __expf(a.y); return r;
}
__device__ __forceinline__ f32x2 rcp2(f32x2 a) {
    f32x2 r; r.x = __builtin_amdgcn_rcpf(a.x); r.y = __builtin_amdgcn_rcpf(a.y); return r;
}
__device__ __forceinline__ nf4 mk4(float a, float b, float c, float d) {
    nf4 r; r.x = a; r.y = b; r.z = c; r.w = d; return r;
}

// Barrier ordering LDS traffic only (lgkmcnt), NOT global stores (vmcnt).
__device__ __forceinline__ void barrier_lds_only() {
    asm volatile("s_waitcnt lgkmcnt(0)\n\ts_barrier" ::: "memory");
}

// Packed 2-sample MLP: weights wave-uniform (SGPR), data f32x2.
__device__ __forceinline__ void mlp7p(const f32x2 x[7],
    const float* __restrict__ W0, const float* __restrict__ b0,
    const float* __restrict__ W1, const float* __restrict__ b1,
    const float* __restrict__ W2, const float* __restrict__ b2,
    const float* __restrict__ W3, const float* __restrict__ b3,
    f32x2 e[3])
{
    const f32x2 zero = splat2(0.0f);
    f32x2 h0[5];
#pragma unroll
    for (int h = 0; h < 5; ++h) {
        f32x2 a = splat2(b0[h]);
#pragma unroll
        for (int f = 0; f < 7; ++f) a = fma2(x[f], splat2(W0[f * 5 + h]), a);
        h0[h] = max2(a, zero);
    }
    f32x2 h1[4];
#pragma unroll
    for (int k = 0; k < 4; ++k) {
        f32x2 a = splat2(b1[k]);
#pragma unroll
        for (int h = 0; h < 5; ++h) a = fma2(h0[h], splat2(W1[h * 4 + k]), a);
        h1[k] = max2(a, zero);
    }
    f32x2 h2[4];
#pragma unroll
    for (int k = 0; k < 4; ++k) {
        f32x2 a = splat2(b2[k]);
#pragma unroll
        for (int h = 0; h < 4; ++h) a = fma2(h1[h], splat2(W2[h * 4 + k]), a);
        h2[k] = max2(a, zero);
    }
    f32x2 l[3];
#pragma unroll
    for (int k = 0; k < 3; ++k) {
        f32x2 a = splat2(b3[k]);
#pragma unroll
        for (int h = 0; h < 4; ++h) a = fma2(h2[h], splat2(W3[h * 3 + k]), a);
        l[k] = a;
    }
    f32x2 m = max2(l[0], max2(l[1], l[2]));
    f32x2 e0 = expc2(l[0] - m);
    f32x2 e1 = expc2(l[1] - m);
    f32x2 e2 = expc2(l[2] - m);
    f32x2 rs = rcp2(e0 + e1 + e2);
    e[0] = e0 * rs; e[1] = e1 * rs; e[2] = e2 * rs;
}

template<int MODE, int REP>
__global__ __launch_bounds__(512, 6) void lps_kernel(
    const float* __restrict__ tau, const float* __restrict__ mu, const float* __restrict__ mu_bar,
    const float* __restrict__ lw, const float* __restrict__ h2o, const float* __restrict__ o3,
    const float* __restrict__ co2, const float* __restrict__ uu, const float* __restrict__ n2o,
    const float* __restrict__ ch4,
    const float* __restrict__ Wd0, const float* __restrict__ bd0,
    const float* __restrict__ Wf0, const float* __restrict__ bf0,
    const float* __restrict__ Wd1, const float* __restrict__ bd1,
    const float* __restrict__ Wf1, const float* __restrict__ bf1,
    const float* __restrict__ Wd2, const float* __restrict__ bd2,
    const float* __restrict__ Wf2, const float* __restrict__ bf2,
    const float* __restrict__ Wd3, const float* __restrict__ bd3,
    const float* __restrict__ Wf3, const float* __restrict__ bf3,
    float* __restrict__ out, int N)
{
    __shared__ __align__(16) nf4 obuf[SPB * ROWA];   // 34816 B

    const int tid  = threadIdx.x;
    const int lane = tid & 63;
    const int wid  = __builtin_amdgcn_readfirstlane(tid >> 6);   // 0..7

    const long long base = (long long)blockIdx.x * SPB;
    const int s0 = (int)base + lane;
    const int s1 = s0 + 64;
    const int i0 = (s0 < N) ? s0 : (N - 1);
    const int i1 = (s1 < N) ? s1 : (N - 1);

    f32x2 mu2, mub2;
    mu2.x  = mu[i0];      mu2.y  = mu[i1];
    mub2.x = mu_bar[i0];  mub2.y = mu_bar[i1];
    const f32x2 rmu2  = rcp2(mu2 + splat2(EPS));
    const f32x2 rmub2 = rcp2(mub2 + splat2(EPS));

    f32x2 cons2[7];
    cons2[0].x = lw[i0];  cons2[0].y = lw[i1];
    cons2[1].x = h2o[i0]; cons2[1].y = h2o[i1];
    cons2[2].x = o3[i0];  cons2[2].y = o3[i1];
    cons2[3].x = co2[i0]; cons2[3].y = co2[i1];
    cons2[4].x = uu[i0];  cons2[4].y = uu[i1];
    cons2[5].x = n2o[i0]; cons2[5].y = n2o[i1];
    cons2[6].x = ch4[i0]; cons2[6].y = ch4[i1];

    int nsamp = N - (int)base;
    if (nsamp > SPB) nsamp = SPB;
    nf4* out4 = (nf4*)out;

    for (int rep = 0; rep < REP; ++rep) {
#pragma unroll
        for (int k = 0; k < 4; ++k) {
            const int c = k * 8 + wid;            // wave-uniform channel
            if (c < NCH) {
                f32x2 tau2;
                tau2.x = tau[(size_t)i0 * NCH + c];
                tau2.y = tau[(size_t)i1 * NCH + c];
                const f32x2 td2 = expc2(-(tau2 * rmu2));
                const f32x2 tf2 = expc2(-(tau2 * rmub2));

                f32x2 ed[3], ef[3];
                if constexpr (MODE != 2) {
                    f32x2 x2[7];
#pragma unroll
                    for (int f = 0; f < 7; ++f) x2[f] = cons2[f] * rmu2;
                    mlp7p(x2, Wd0 + c * 35, bd0 + c * 5, Wd1 + c * 20, bd1 + c * 4,
                              Wd2 + c * 16, bd2 + c * 4, Wd3 + c * 12, bd3 + c * 3, ed);
#pragma unroll
                    for (int f = 0; f < 7; ++f) x2[f] = cons2[f] * rmub2;
                    mlp7p(x2, Wf0 + c * 35, bf0 + c * 5, Wf1 + c * 20, bf1 + c * 4,
                              Wf2 + c * 16, bf2 + c * 4, Wf3 + c * 12, bf3 + c * 3, ef);
                } else {
                    // stores-only: trivial values, no MLP
                    ed[0] = td2; ed[1] = tf2; ed[2] = td2;
                    ef[0] = tf2; ef[1] = td2; ef[2] = tf2;
                }

                const int r = (c - k * 8) * 2;    // local slot 0..15
                obuf[lane * ROWA + r]            = mk4(td2.x, tf2.x, ed[0].x, ed[1].x);
                obuf[lane * ROWA + r + 1]        = mk4(ed[2].x, ef[0].x, ef[1].x, ef[2].x);
                obuf[(lane + 64) * ROWA + r]     = mk4(td2.y, tf2.y, ed[0].y, ed[1].y);
                obuf[(lane + 64) * ROWA + r + 1] = mk4(ed[2].y, ef[0].y, ef[1].y, ef[2].y);
            }

            barrier_lds_only();

            if (nsamp > 0) {
                if constexpr (MODE != 1) {
                    // real flush to global (fire-and-forget)
                    if (k < 3) {
                        const int tot = nsamp * 16;
                        for (int i = tid; i < tot; i += 512) {
                            const int s = i >> 4, rr = i & 15;
                            out4[(base + s) * 58 + k * 16 + rr] = obuf[s * ROWA + rr];
                        }
                    } else {
                        const int tot = nsamp * 10;
                        for (int i = tid; i < tot; i += 512) {
                            const int s = i / 10, rr = i - s * 10;
                            out4[(base + s) * 58 + 48 + rr] = obuf[s * ROWA + rr];
                        }
                    }
                } else {
                    // compute-only: same LDS reads, values kept alive, no global store
                    if (k < 3) {
                        const int tot = nsamp * 16;
                        for (int i = tid; i < tot; i += 512) {
                            const int s = i >> 4, rr = i & 15;
                            nf4 v = obuf[s * ROWA + rr];
                            asm volatile("" :: "v"(v.x), "v"(v.y), "v"(v.z), "v"(v.w));
                        }
                    } else {
                        const int tot = nsamp * 10;
                        for (int i = tid; i < tot; i += 512) {
                            const int s = i / 10, rr = i - s * 10;
                            nf4 v = obuf[s * ROWA + rr];
                            asm volatile("" :: "v"(v.x), "v"(v.y), "v"(v.z), "v"(v.w));
                        }
                    }
                }
            }

            barrier_lds_only();   // flush reads done -> obuf reusable
        }
    }
}

extern "C" void kernel_launch(void* const* d_in, const int* in_sizes, int n_in,
                              void* d_out, int out_size, void* d_ws, size_t ws_size,
                              hipStream_t stream) {
    const float* tau    = (const float*)d_in[0];
    const float* mu     = (const float*)d_in[1];
    const float* mu_bar = (const float*)d_in[2];
    const float* lw     = (const float*)d_in[3];
    const float* h2o    = (const float*)d_in[4];
    const float* o3     = (const float*)d_in[5];
    const float* co2    = (const float*)d_in[6];
    const float* uu     = (const float*)d_in[7];
    const float* n2o    = (const float*)d_in[8];
    const float* ch4    = (const float*)d_in[9];

    const float* Wd0 = (const float*)d_in[10];
    const float* bd0 = (const float*)d_in[11];
    const float* Wf0 = (const float*)d_in[12];
    const float* bf0 = (const float*)d_in[13];
    const float* Wd1 = (const float*)d_in[14];
    const float* bd1 = (const float*)d_in[15];
    const float* Wf1 = (const float*)d_in[16];
    const float* bf1 = (const float*)d_in[17];
    const float* Wd2 = (const float*)d_in[18];
    const float* bd2 = (const float*)d_in[19];
    const float* Wf2 = (const float*)d_in[20];
    const float* bf2 = (const float*)d_in[21];
    const float* Wd3 = (const float*)d_in[22];
    const float* bd3 = (const float*)d_in[23];
    const float* Wf3 = (const float*)d_in[24];
    const float* bf3 = (const float*)d_in[25];

    float* out = (float*)d_out;
    int N = in_sizes[1];  // mu has N elements

    int blocks = (N + SPB - 1) / SPB;

    // (A) stores-only x4: write path + barriers, no MLP
    lps_kernel<2, 4><<<blocks, 512, 0, stream>>>(
        tau, mu, mu_bar, lw, h2o, o3, co2, uu, n2o, ch4,
        Wd0, bd0, Wf0, bf0, Wd1, bd1, Wf1, bf1,
        Wd2, bd2, Wf2, bf2, Wd3, bd3, Wf3, bf3, out, N);

    // (B) compute-only x4: full math + LDS + barriers, no global stores
    lps_kernel<1, 4><<<blocks, 512, 0, stream>>>(
        tau, mu, mu_bar, lw, h2o, o3, co2, uu, n2o, ch4,
        Wd0, bd0, Wf0, bf0, Wd1, bd1, Wf1, bf1,
        Wd2, bd2, Wf2, bf2, Wd3, bd3, Wf3, bf3, out, N);

    // (C) real kernel: correct output, runs last
    lps_kernel<0, 1><<<blocks, 512, 0, stream>>>(
        tau, mu, mu_bar, lw, h2o, o3, co2, uu, n2o, ch4,
        Wd0, bd0, Wf0, bf0, Wd1, bd1, Wf1, bf1,
        Wd2, bd2, Wf2, bf2, Wd3, bd3, Wf3, bf3, out, N);
}

// Round 19
// 77.146 us; speedup vs baseline: 5.8439x; 5.8439x over previous
//
#include <hip/hip_runtime.h>

#define EPS 1e-7f
#define NCH 29
#define SPB 128          // samples per block: 64 lanes x 2 packed (group0, group1)
#define ROWA 17          // padded float4 stride per sample in chunk staging buffer

// MLP sizes: 7 -> 5 -> 4 -> 4 -> 3, per-channel weights.
// W0: [c][7][5]  b0: [c][5]
// W1: [c][5][4]  b1: [c][4]
// W2: [c][4][4]  b2: [c][4]
// W3: [c][4][3]  b3: [c][3]

typedef float f32x2 __attribute__((ext_vector_type(2)));
typedef float nf4   __attribute__((ext_vector_type(4)));

__device__ __forceinline__ f32x2 splat2(float v) { f32x2 r; r.x = v; r.y = v; return r; }
__device__ __forceinline__ f32x2 fma2(f32x2 a, f32x2 b, f32x2 c) {
    return __builtin_elementwise_fma(a, b, c);
}
__device__ __forceinline__ f32x2 max2(f32x2 a, f32x2 b) {
    return __builtin_elementwise_max(a, b);
}
__device__ __forceinline__ f32x2 expc2(f32x2 a) {
    f32x2 r; r.x = __expf(a.x); r.y = __expf(a.y); return r;
}
__device__ __forceinline__ f32x2 rcp2(f32x2 a) {
    f32x2 r; r.x = __builtin_amdgcn_rcpf(a.x); r.y = __builtin_amdgcn_rcpf(a.y); return r;
}
__device__ __forceinline__ nf4 mk4(float a, float b, float c, float d) {
    nf4 r; r.x = a; r.y = b; r.z = c; r.w = d; return r;
}

// Barrier ordering LDS traffic only (lgkmcnt), NOT global stores (vmcnt).
__device__ __forceinline__ void barrier_lds_only() {
    asm volatile("s_waitcnt lgkmcnt(0)\n\ts_barrier" ::: "memory");
}

// Packed 2-sample MLP: weights wave-uniform (SGPR), data f32x2.
__device__ __forceinline__ void mlp7p(const f32x2 x[7],
    const float* __restrict__ W0, const float* __restrict__ b0,
    const float* __restrict__ W1, const float* __restrict__ b1,
    const float* __restrict__ W2, const float* __restrict__ b2,
    const float* __restrict__ W3, const float* __restrict__ b3,
    f32x2 e[3])
{
    const f32x2 zero = splat2(0.0f);
    f32x2 h0[5];
#pragma unroll
    for (int h = 0; h < 5; ++h) {
        f32x2 a = splat2(b0[h]);
#pragma unroll
        for (int f = 0; f < 7; ++f) a = fma2(x[f], splat2(W0[f * 5 + h]), a);
        h0[h] = max2(a, zero);
    }
    f32x2 h1[4];
#pragma unroll
    for (int k = 0; k < 4; ++k) {
        f32x2 a = splat2(b1[k]);
#pragma unroll
        for (int h = 0; h < 5; ++h) a = fma2(h0[h], splat2(W1[h * 4 + k]), a);
        h1[k] = max2(a, zero);
    }
    f32x2 h2[4];
#pragma unroll
    for (int k = 0; k < 4; ++k) {
        f32x2 a = splat2(b2[k]);
#pragma unroll
        for (int h = 0; h < 4; ++h) a = fma2(h1[h], splat2(W2[h * 4 + k]), a);
        h2[k] = max2(a, zero);
    }
    f32x2 l[3];
#pragma unroll
    for (int k = 0; k < 3; ++k) {
        f32x2 a = splat2(b3[k]);
#pragma unroll
        for (int h = 0; h < 4; ++h) a = fma2(h2[h], splat2(W3[h * 3 + k]), a);
        l[k] = a;
    }
    f32x2 m = max2(l[0], max2(l[1], l[2]));
    f32x2 e0 = expc2(l[0] - m);
    f32x2 e1 = expc2(l[1] - m);
    f32x2 e2 = expc2(l[2] - m);
    f32x2 rs = rcp2(e0 + e1 + e2);
    e[0] = e0 * rs; e[1] = e1 * rs; e[2] = e2 * rs;
}

// cap 102 VGPR (5 waves/EU): room for the +8 VGPR tau hoist, no spill.
__global__ __launch_bounds__(512, 5) void lps_kernel(
    const float* __restrict__ tau, const float* __restrict__ mu, const float* __restrict__ mu_bar,
    const float* __restrict__ lw, const float* __restrict__ h2o, const float* __restrict__ o3,
    const float* __restrict__ co2, const float* __restrict__ uu, const float* __restrict__ n2o,
    const float* __restrict__ ch4,
    const float* __restrict__ Wd0, const float* __restrict__ bd0,
    const float* __restrict__ Wf0, const float* __restrict__ bf0,
    const float* __restrict__ Wd1, const float* __restrict__ bd1,
    const float* __restrict__ Wf1, const float* __restrict__ bf1,
    const float* __restrict__ Wd2, const float* __restrict__ bd2,
    const float* __restrict__ Wf2, const float* __restrict__ bf2,
    const float* __restrict__ Wd3, const float* __restrict__ bd3,
    const float* __restrict__ Wf3, const float* __restrict__ bf3,
    float* __restrict__ out, int N)
{
    __shared__ __align__(16) nf4 obuf[SPB * ROWA];   // 34816 B

    const int tid  = threadIdx.x;
    const int lane = tid & 63;
    const int wid  = __builtin_amdgcn_readfirstlane(tid >> 6);   // 0..7

    const long long base = (long long)blockIdx.x * SPB;
    const int s0 = (int)base + lane;
    const int s1 = s0 + 64;
    const int i0 = (s0 < N) ? s0 : (N - 1);
    const int i1 = (s1 < N) ? s1 : (N - 1);

    f32x2 mu2, mub2;
    mu2.x  = mu[i0];      mu2.y  = mu[i1];
    mub2.x = mu_bar[i0];  mub2.y = mu_bar[i1];
    const f32x2 rmu2  = rcp2(mu2 + splat2(EPS));
    const f32x2 rmub2 = rcp2(mub2 + splat2(EPS));

    f32x2 cons2[7];
    cons2[0].x = lw[i0];  cons2[0].y = lw[i1];
    cons2[1].x = h2o[i0]; cons2[1].y = h2o[i1];
    cons2[2].x = o3[i0];  cons2[2].y = o3[i1];
    cons2[3].x = co2[i0]; cons2[3].y = co2[i1];
    cons2[4].x = uu[i0];  cons2[4].y = uu[i1];
    cons2[5].x = n2o[i0]; cons2[5].y = n2o[i1];
    cons2[6].x = ch4[i0]; cons2[6].y = ch4[i1];

    // ---- THE fix: hoist ALL remaining global loads (tau, 4 chunks) into the
    // prologue, BEFORE any global store is issued. Per-chunk compute then has
    // zero vmem ops, so no s_waitcnt vmcnt inside the loop -- chunk k's store
    // drain proceeds underneath chunk k+1's compute instead of blocking it
    // (vmcnt is a shared in-order counter: a load-use after stores would wait
    // for every prior store to retire through the saturated write path).
    f32x2 tau2v[4];
#pragma unroll
    for (int k = 0; k < 4; ++k) {
        const int c  = k * 8 + wid;
        const int cc = (c < NCH) ? c : 0;
        tau2v[k].x = tau[(size_t)i0 * NCH + cc];
        tau2v[k].y = tau[(size_t)i1 * NCH + cc];
    }

    int nsamp = N - (int)base;
    if (nsamp > SPB) nsamp = SPB;
    nf4* out4 = (nf4*)out;

    // 4 chunk-phases: compute 8 channels -> lgkm barrier -> issue stores
    // (fire-and-forget) -> lgkm barrier. No vmcnt wait anywhere in the loop.
#pragma unroll
    for (int k = 0; k < 4; ++k) {
        const int c = k * 8 + wid;            // wave-uniform channel
        if (c < NCH) {
            const f32x2 td2 = expc2(-(tau2v[k] * rmu2));
            const f32x2 tf2 = expc2(-(tau2v[k] * rmub2));

            f32x2 x2[7];
            f32x2 ed[3], ef[3];
#pragma unroll
            for (int f = 0; f < 7; ++f) x2[f] = cons2[f] * rmu2;
            mlp7p(x2, Wd0 + c * 35, bd0 + c * 5, Wd1 + c * 20, bd1 + c * 4,
                      Wd2 + c * 16, bd2 + c * 4, Wd3 + c * 12, bd3 + c * 3, ed);
#pragma unroll
            for (int f = 0; f < 7; ++f) x2[f] = cons2[f] * rmub2;
            mlp7p(x2, Wf0 + c * 35, bf0 + c * 5, Wf1 + c * 20, bf1 + c * 4,
                      Wf2 + c * 16, bf2 + c * 4, Wf3 + c * 12, bf3 + c * 3, ef);

            const int r = (c - k * 8) * 2;    // local slot 0..15
            obuf[lane * ROWA + r]            = mk4(td2.x, tf2.x, ed[0].x, ed[1].x);
            obuf[lane * ROWA + r + 1]        = mk4(ed[2].x, ef[0].x, ef[1].x, ef[2].x);
            obuf[(lane + 64) * ROWA + r]     = mk4(td2.y, tf2.y, ed[0].y, ed[1].y);
            obuf[(lane + 64) * ROWA + r + 1] = mk4(ed[2].y, ef[0].y, ef[1].y, ef[2].y);
        }

        barrier_lds_only();

        // issue chunk-k stores (fire-and-forget; drain overlaps chunk k+1)
        if (nsamp > 0) {
            if (k < 3) {
                const int tot = nsamp * 16;
                for (int i = tid; i < tot; i += 512) {
                    const int s = i >> 4, rr = i & 15;
                    out4[(base + s) * 58 + k * 16 + rr] = obuf[s * ROWA + rr];
                }
            } else {
                const int tot = nsamp * 10;   // 5 channels -> 10 f4 per sample
                for (int i = tid; i < tot; i += 512) {
                    const int s = i / 10, rr = i - s * 10;
                    out4[(base + s) * 58 + 48 + rr] = obuf[s * ROWA + rr];
                }
            }
        }

        barrier_lds_only();   // flush reads done -> obuf reusable
    }
}

extern "C" void kernel_launch(void* const* d_in, const int* in_sizes, int n_in,
                              void* d_out, int out_size, void* d_ws, size_t ws_size,
                              hipStream_t stream) {
    const float* tau    = (const float*)d_in[0];
    const float* mu     = (const float*)d_in[1];
    const float* mu_bar = (const float*)d_in[2];
    const float* lw     = (const float*)d_in[3];
    const float* h2o    = (const float*)d_in[4];
    const float* o3     = (const float*)d_in[5];
    const float* co2    = (const float*)d_in[6];
    const float* uu     = (const float*)d_in[7];
    const float* n2o    = (const float*)d_in[8];
    const float* ch4    = (const float*)d_in[9];

    const float* Wd0 = (const float*)d_in[10];
    const float* bd0 = (const float*)d_in[11];
    const float* Wf0 = (const float*)d_in[12];
    const float* bf0 = (const float*)d_in[13];
    const float* Wd1 = (const float*)d_in[14];
    const float* bd1 = (const float*)d_in[15];
    const float* Wf1 = (const float*)d_in[16];
    const float* bf1 = (const float*)d_in[17];
    const float* Wd2 = (const float*)d_in[18];
    const float* bd2 = (const float*)d_in[19];
    const float* Wf2 = (const float*)d_in[20];
    const float* bf2 = (const float*)d_in[21];
    const float* Wd3 = (const float*)d_in[22];
    const float* bd3 = (const float*)d_in[23];
    const float* Wf3 = (const float*)d_in[24];
    const float* bf3 = (const float*)d_in[25];

    float* out = (float*)d_out;
    int N = in_sizes[1];  // mu has N elements

    int blocks = (N + SPB - 1) / SPB;
    lps_kernel<<<blocks, 512, 0, stream>>>(
        tau, mu, mu_bar, lw, h2o, o3, co2, uu, n2o, ch4,
        Wd0, bd0, Wf0, bf0, Wd1, bd1, Wf1, bf1,
        Wd2, bd2, Wf2, bf2, Wd3, bd3, Wf3, bf3,
        out, N);
}